// Round 9
// baseline (9353.238 us; speedup 1.0000x reference)
//
#include <hip/hip_runtime.h>
#include <math.h>

#define DD   512
#define BATCH 128
#define NTOK 251
#define NHEAD 4
#define HD   128

#define GF_ADDC   1
#define GF_BIAS   2
#define GF_GELU   4
#define GF_OBF16  8
#define GF_LNA    16
#define GF_STATS  32

typedef unsigned short ushort_t;
typedef __attribute__((ext_vector_type(8))) short bf16x8;
typedef __attribute__((ext_vector_type(4))) float f32x4;

__constant__ int c_cols[3][12] = {
  {8,10,12,22,24,26, 9,11,13,23,25,27},
  {2, 4, 6,28,30,32, 3, 5, 7,29,31,33},
  {0,14,16,18,20, 1,15,17,19,21, 0, 0}
};
__constant__ int c_ncols[3] = {12,12,10};

__device__ __forceinline__ float gelu_f(float v){
  return 0.5f*v*(1.0f + erff(v*0.70710678118654752440f));
}
__device__ __forceinline__ ushort_t f2b(float v){   // RNE float->bf16
  union { float f; unsigned u; } x; x.f = v;
  unsigned r = x.u + 0x7fffu + ((x.u >> 16) & 1u);
  return (ushort_t)(r >> 16);
}
__device__ __forceinline__ void async_copy16(const void* g, void* l){
  __builtin_amdgcn_global_load_lds(
      (const __attribute__((address_space(1))) unsigned*)g,
      (__attribute__((address_space(3))) unsigned*)l, 16, 0, 0);
}

// ---- weight convert+transpose (+optional per-k gamma scale) ----
__global__ __launch_bounds__(256) void wtrans_kernel(ushort_t* __restrict__ dst,
                                                     const float* __restrict__ src,
                                                     const float* __restrict__ gv,
                                                     long ldD, long dstPlane, long srcPlane,
                                                     long gStride){
  __shared__ float tile[32][33];
  long mat = blockIdx.z;
  const float* S = src + mat*srcPlane;
  ushort_t* D = dst + mat*dstPlane;
  const float* gp = gv ? gv + mat*gStride : nullptr;
  int n0 = blockIdx.x*32, k0 = blockIdx.y*32;
  for (int r = threadIdx.y; r < 32; r += 8){
    float sc = gp ? gp[k0+r] : 1.0f;
    tile[r][threadIdx.x] = S[(long)(k0+r)*DD + n0 + threadIdx.x] * sc;
  }
  __syncthreads();
  for (int r = threadIdx.y; r < 32; r += 8)
    D[(long)(n0+r)*ldD + k0 + threadIdx.x] = f2b(tile[threadIdx.x][r]);
}

// ---- bias prep: outb[wi][n] = base[wi][n] + sum_k beta[wi][k]*W[wi][k][n] ----
__global__ __launch_bounds__(256) void bias_prep(float* __restrict__ outb,
    const float* __restrict__ base, const float* __restrict__ beta,
    const float* __restrict__ W, long outStride, int N){
  int wi = blockIdx.y;
  const float* Wp = W + (long)wi*512*N;
  const float* bp = beta + (long)wi*512;
  int n = blockIdx.x*256 + threadIdx.x;
  if (n >= N) return;
  float acc = base ? base[(long)wi*N + n] : 0.0f;
  for (int k = 0; k < 512; k++) acc = fmaf(bp[k], Wp[(long)k*N + n], acc);
  outb[(long)wi*outStride + n] = acc;
}

// ---- embed (fp32 h) + LN stats (slot 0; slots 1-7 zeroed) ----
__global__ void embed_kernel(float* __restrict__ h, float2* __restrict__ stats,
                             const float* __restrict__ x,
                             const float* __restrict__ w, const float* __restrict__ bias,
                             const float* __restrict__ pos, const float* __restrict__ cls,
                             int br, int b0){
  __shared__ float sred[2][2];
  long bt = blockIdx.x;
  int  t  = (int)(bt % NTOK);
  long b  = b0 + bt / NTOK;
  float* outr = h + bt*DD;
  float s = 0.0f, s2 = 0.0f;
  if (t == 0){
    for (int d = threadIdx.x; d < DD; d += 128){
      float v = cls[d] + pos[d];
      outr[d] = v; s += v; s2 += v*v;
    }
  } else {
    const float* xr = x + (b*(NTOK-1) + (t-1))*34;
    int nc = c_ncols[br];
    float xs[12];
    for (int j = 0; j < 12; j++) xs[j] = (j < nc) ? xr[c_cols[br][j]] : 0.0f;
    const float* posr = pos + (long)t*DD;
    for (int d = threadIdx.x; d < DD; d += 128){
      float acc = bias[d] + posr[d];
      for (int j = 0; j < nc; j++) acc = fmaf(xs[j], w[j*DD + d], acc);
      outr[d] = acc; s += acc; s2 += acc*acc;
    }
  }
  #pragma unroll
  for (int o = 32; o > 0; o >>= 1){ s += __shfl_down(s, o, 64); s2 += __shfl_down(s2, o, 64); }
  int w64 = threadIdx.x >> 6;
  if ((threadIdx.x & 63) == 0){ sred[w64][0] = s; sred[w64][1] = s2; }
  __syncthreads();
  if (threadIdx.x == 0)
    stats[bt*8] = make_float2(sred[0][0]+sred[1][0], sred[0][1]+sred[1][1]);
  else if (threadIdx.x < 8)
    stats[bt*8 + threadIdx.x] = make_float2(0.0f, 0.0f);
}

// ---- V^T per (b,h): vt[plane][d][t] (ld 256, t-pad zeroed) ----
__global__ __launch_bounds__(256) void vtrans_kernel(ushort_t* __restrict__ vt,
                                                     const ushort_t* __restrict__ v){
  __shared__ ushort_t tile[32][33];
  int b = blockIdx.z >> 2, hh = blockIdx.z & 3;
  const ushort_t* src = v + (long)b*NTOK*1536 + hh*HD;
  ushort_t* dst = vt + (long)blockIdx.z*HD*256;
  int t0 = blockIdx.y*32, d0 = blockIdx.x*32;
  int tx = threadIdx.x, ty = threadIdx.y;
  for (int r = ty; r < 32; r += 8){
    int t = t0 + r;
    tile[r][tx] = (t < NTOK) ? src[(long)t*1536 + d0 + tx] : (ushort_t)0;
  }
  __syncthreads();
  for (int r = ty; r < 32; r += 8)
    dst[(long)(d0 + r)*256 + t0 + tx] = tile[tx][r];
}

// ---- fused flash attention (Q hoisted to regs) ----
__global__ __launch_bounds__(256) void flash_kernel(
    ushort_t* __restrict__ o, const ushort_t* __restrict__ qkv,
    const ushort_t* __restrict__ vt, float alpha){
  __shared__ __align__(16) ushort_t Ps[64*136];
  int bh = blockIdx.z, b = bh>>2, hh = bh&3;
  int q0 = blockIdx.x*64;
  const ushort_t* Qg = qkv + (long)b*NTOK*1536 + hh*HD;
  const ushort_t* Kg = Qg + 512;
  const ushort_t* Vg = vt + (long)bh*HD*256;
  int tid = threadIdx.x, w = tid>>6, lane = tid&63;
  int quad = lane>>4, l15 = lane&15;
  int qrow = q0 + w*16 + l15;
  const ushort_t* qptr = Qg + (long)qrow*1536;
  bool qvalid = qrow < NTOK;

  bf16x8 qf[4];
  #pragma unroll
  for (int kc = 0; kc < 4; kc++){
    if (qvalid) qf[kc] = *(const bf16x8*)(qptr + kc*32 + quad*8);
    else        qf[kc] = (bf16x8){0,0,0,0,0,0,0,0};
  }

  f32x4 oacc[8] = {};
  float mrow[4], lrow[4];
  #pragma unroll
  for (int r = 0; r < 4; r++){ mrow[r] = -1e30f; lrow[r] = 0.0f; }

  #pragma unroll
  for (int nt = 0; nt < 2; nt++){
    f32x4 s[8] = {};
    #pragma unroll
    for (int kc = 0; kc < 4; kc++){
      #pragma unroll
      for (int j = 0; j < 8; j++){
        long t = nt*128 + j*16 + l15;
        bf16x8 bf = *(const bf16x8*)(Kg + t*1536 + kc*32 + quad*8);
        s[j] = __builtin_amdgcn_mfma_f32_16x16x32_bf16(qf[kc], bf, s[j], 0, 0, 0);
      }
    }
    #pragma unroll
    for (int r = 0; r < 4; r++){
      float mx = -1e30f;
      #pragma unroll
      for (int j = 0; j < 8; j++){
        int t = nt*128 + j*16 + l15;
        float v = (t < NTOK) ? s[j][r]*alpha : -1e30f;
        s[j][r] = v; mx = fmaxf(mx, v);
      }
      mx = fmaxf(mx, __shfl_xor(mx,1)); mx = fmaxf(mx, __shfl_xor(mx,2));
      mx = fmaxf(mx, __shfl_xor(mx,4)); mx = fmaxf(mx, __shfl_xor(mx,8));
      float Mn  = fmaxf(mrow[r], mx);
      float fac = __expf(mrow[r] - Mn);
      mrow[r] = Mn;
      float sum = 0.0f;
      #pragma unroll
      for (int j = 0; j < 8; j++){
        float e = __expf(s[j][r] - Mn);
        s[j][r] = e; sum += e;
      }
      sum += __shfl_xor(sum,1); sum += __shfl_xor(sum,2);
      sum += __shfl_xor(sum,4); sum += __shfl_xor(sum,8);
      lrow[r] = lrow[r]*fac + sum;
      #pragma unroll
      for (int j = 0; j < 8; j++) oacc[j][r] *= fac;
      #pragma unroll
      for (int j = 0; j < 8; j++)
        Ps[(w*16 + quad*4 + r)*136 + j*16 + l15] = f2b(s[j][r]);
    }
    #pragma unroll
    for (int tc = 0; tc < 4; tc++){
      bf16x8 af = *(const bf16x8*)&Ps[(w*16 + l15)*136 + tc*32 + quad*8];
      #pragma unroll
      for (int j = 0; j < 8; j++){
        bf16x8 bf = *(const bf16x8*)(Vg + (long)(j*16 + l15)*256 + nt*128 + tc*32 + quad*8);
        oacc[j] = __builtin_amdgcn_mfma_f32_16x16x32_bf16(af, bf, oacc[j], 0, 0, 0);
      }
    }
  }
  #pragma unroll
  for (int r = 0; r < 4; r++){
    int q = q0 + w*16 + quad*4 + r;
    if (q >= NTOK) continue;
    float invl = 1.0f / lrow[r];
    ushort_t* orow = o + ((long)b*NTOK + q)*512 + hh*128;
    #pragma unroll
    for (int j = 0; j < 8; j++)
      orow[j*16 + l15] = f2b(oacc[j][r]*invl);
  }
}

// ---- MFMA GEMM: C = A[M,K] @ Bt[N,K]^T; block 128x128, wave 64x64 ----
// GF_LNA: A staged from fp32 h + per-row LN stats (gamma folded into Bt, beta into bias).
// GF_STATS: epilogue writes per-row partial (sum,sumsq) to stOut[row][by*2+(wn>>6)].
__global__ __launch_bounds__(256) void gemm_bt_mfma(
    const ushort_t* __restrict__ A, const float* __restrict__ Af32,
    const float2* __restrict__ stIn, float2* __restrict__ stOut,
    long lda,
    const ushort_t* __restrict__ Bt, long ldb,
    void* __restrict__ Cp, long ldc,
    const float* __restrict__ bias, int M, int N, int K, int flags, float alpha){
  __shared__ __align__(16) ushort_t As[128*32];
  __shared__ __align__(16) ushort_t Bs[128*32];

  int tid = threadIdx.x;
  int wave = tid >> 6, lane = tid & 63;
  int quad = lane >> 4, l15 = lane & 15;
  int wm = (wave >> 1) * 64, wn = (wave & 1) * 64;
  int m0 = blockIdx.x * 128, n0 = blockIdx.y * 128;

  f32x4 acc[4][4] = {};
  bool fast = (m0 + 128 <= M) && (n0 + 128 <= N) && ((K & 31) == 0);

  float muv[2] = {0,0}, rsv[2] = {1,1};
  if (flags & GF_LNA){          // K==512 for all LNA users
    #pragma unroll
    for (int c = 0; c < 2; c++){
      int gm = m0 + c*64 + (tid>>2);
      float s = 0.0f, s2 = 0.0f;
      if (gm < M){
        const float4* sp = (const float4*)(stIn + (long)gm*8);
        #pragma unroll
        for (int u = 0; u < 4; u++){ float4 v = sp[u]; s += v.x + v.z; s2 += v.y + v.w; }
      }
      float mu = s*(1.0f/512.0f);
      float var = s2*(1.0f/512.0f) - mu*mu;
      muv[c] = mu; rsv[c] = rsqrtf(var + 1e-5f);
    }
  }

  if (fast){
    int rloc = wave*16 + (lane >> 2);
    int pos  = lane & 3;
    const ushort_t* B0 = Bt + (long)n0*ldb;
    for (int k0 = 0; k0 < K; k0 += 32){
      #pragma unroll
      for (int c = 0; c < 2; c++){
        int r  = c*64 + rloc;
        long koff = k0 + ((pos ^ ((r >> 1) & 3)) << 3);
        async_copy16(B0 + (long)r*ldb + koff, (void*)&Bs[(c*256 + wave*64)*8]);
      }
      if (flags & GF_LNA){
        #pragma unroll
        for (int c = 0; c < 2; c++){
          int r = c*64 + (tid>>2);
          int kc8 = (((tid&3) ^ ((r >> 1) & 3)) << 3);
          const float* hr = Af32 + (long)(m0+r)*lda + k0 + kc8;
          float4 f0 = *(const float4*)hr;
          float4 f1 = *(const float4*)(hr+4);
          float tv[8] = {f0.x,f0.y,f0.z,f0.w,f1.x,f1.y,f1.z,f1.w};
          ushort_t o8[8];
          #pragma unroll
          for (int e = 0; e < 8; e++) o8[e] = f2b((tv[e]-muv[c])*rsv[c]);
          *(uint4*)&As[r*32 + (tid&3)*8] = *(const uint4*)o8;
        }
      } else {
        const ushort_t* A0 = A + (long)m0*lda;
        #pragma unroll
        for (int c = 0; c < 2; c++){
          int r  = c*64 + rloc;
          long koff = k0 + ((pos ^ ((r >> 1) & 3)) << 3);
          async_copy16(A0 + (long)r*lda + koff, (void*)&As[(c*256 + wave*64)*8]);
        }
      }
      __syncthreads();
      bf16x8 af[4], bfv[4];
      #pragma unroll
      for (int i = 0; i < 4; i++){
        int row = wm + i*16 + l15;
        af[i] = *(const bf16x8*)&As[row*32 + ((quad ^ ((row>>1)&3)) << 3)];
      }
      #pragma unroll
      for (int j = 0; j < 4; j++){
        int row = wn + j*16 + l15;
        bfv[j] = *(const bf16x8*)&Bs[row*32 + ((quad ^ ((row>>1)&3)) << 3)];
      }
      #pragma unroll
      for (int i = 0; i < 4; i++)
        #pragma unroll
        for (int j = 0; j < 4; j++)
          acc[i][j] = __builtin_amdgcn_mfma_f32_16x16x32_bf16(af[i], bfv[j], acc[i][j], 0, 0, 0);
      __syncthreads();
    }
  } else {
    int nk = (K + 31) >> 5;
    for (int kt = 0; kt < nk; kt++){
      int k0 = kt << 5;
      #pragma unroll
      for (int c = 0; c < 2; c++){
        int q = c*256 + tid;
        int r = q >> 2;
        int gk = k0 + (((q & 3) ^ ((r >> 1) & 3)) << 3);
        int gm = m0 + r;
        if (flags & GF_LNA){
          ushort_t o8[8];
          #pragma unroll
          for (int e = 0; e < 8; e++){
            int kk = gk + e;
            bool ok = (gm < M && kk < K);
            float hv = ok ? Af32[(long)gm*lda + kk] : 0.0f;
            o8[e] = ok ? f2b((hv - muv[c])*rsv[c]) : (ushort_t)0;
          }
          *(uint4*)&As[r*32 + (q & 3)*8] = *(const uint4*)o8;
        } else {
          uint4 va;
          if (gm < M && gk + 8 <= K){
            va = *(const uint4*)(A + (long)gm*lda + gk);
          } else {
            ushort_t t[8];
            #pragma unroll
            for (int e = 0; e < 8; e++){
              int kk = gk + e;
              t[e] = (gm < M && kk < K) ? A[(long)gm*lda + kk] : (ushort_t)0;
            }
            va = *(const uint4*)t;
          }
          *(uint4*)&As[r*32 + (q & 3)*8] = va;
        }
        {
          int gn = n0 + r;
          uint4 vb;
          if (gn < N && gk + 8 <= K){
            vb = *(const uint4*)(Bt + (long)gn*ldb + gk);
          } else {
            ushort_t t[8];
            #pragma unroll
            for (int e = 0; e < 8; e++){
              int kk = gk + e;
              t[e] = (gn < N && kk < K) ? Bt[(long)gn*ldb + kk] : (ushort_t)0;
            }
            vb = *(const uint4*)t;
          }
          *(uint4*)&Bs[r*32 + (q & 3)*8] = vb;
        }
      }
      __syncthreads();
      bf16x8 af[4], bfv[4];
      #pragma unroll
      for (int i = 0; i < 4; i++){
        int row = wm + i*16 + l15;
        af[i] = *(const bf16x8*)&As[row*32 + ((quad ^ ((row>>1)&3)) << 3)];
      }
      #pragma unroll
      for (int j = 0; j < 4; j++){
        int row = wn + j*16 + l15;
        bfv[j] = *(const bf16x8*)&Bs[row*32 + ((quad ^ ((row>>1)&3)) << 3)];
      }
      #pragma unroll
      for (int i = 0; i < 4; i++)
        #pragma unroll
        for (int j = 0; j < 4; j++)
          acc[i][j] = __builtin_amdgcn_mfma_f32_16x16x32_bf16(af[i], bfv[j], acc[i][j], 0, 0, 0);
      __syncthreads();
    }
  }

  // epilogue: C/D layout col=lane&15, row=quad*4+reg
  float sacc[4][4] = {}, s2acc[4][4] = {};
  #pragma unroll
  for (int i = 0; i < 4; i++){
    int rbase = m0 + wm + i*16 + quad*4;
    #pragma unroll
    for (int j = 0; j < 4; j++){
      int gn = n0 + wn + j*16 + l15;
      if (gn >= N) continue;
      #pragma unroll
      for (int r = 0; r < 4; r++){
        int gm = rbase + r;
        if (gm >= M) continue;
        float v = acc[i][j][r] * alpha;
        if (flags & GF_BIAS) v += bias[gn];
        if (flags & GF_ADDC) v += ((float*)Cp)[(long)gm*ldc + gn];
        if (flags & GF_GELU) v = gelu_f(v);
        sacc[i][r] += v; s2acc[i][r] += v*v;
        if (flags & GF_OBF16){
          ((ushort_t*)Cp)[(long)gm*ldc + gn] = f2b(v);
        } else {
          ((float*)Cp)[(long)gm*ldc + gn] = v;
        }
      }
    }
  }
  if (flags & GF_STATS){
    int slot = blockIdx.y*2 + (wn >> 6);
    #pragma unroll
    for (int i = 0; i < 4; i++){
      #pragma unroll
      for (int r = 0; r < 4; r++){
        int gm = m0 + wm + i*16 + quad*4 + r;
        float s = sacc[i][r], s2 = s2acc[i][r];
        s  += __shfl_xor(s,1);  s  += __shfl_xor(s,2);  s  += __shfl_xor(s,4);  s  += __shfl_xor(s,8);
        s2 += __shfl_xor(s2,1); s2 += __shfl_xor(s2,2); s2 += __shfl_xor(s2,4); s2 += __shfl_xor(s2,8);
        if (l15 == 0 && gm < M) stOut[(long)gm*8 + slot] = make_float2(s, s2);
      }
    }
  }
}

__global__ void copy_cls(ushort_t* __restrict__ cat, const float* __restrict__ h,
                         int br, int b0){
  long b = blockIdx.x;
  int d = threadIdx.x;            // block 512
  cat[(b0+b)*1536 + (long)br*512 + d] = f2b(h[b*(long)NTOK*DD + d]);
}

__global__ void head2_kernel(float* __restrict__ out, const float* __restrict__ hid,
                             const float* __restrict__ w2, const float* __restrict__ b2){
  __shared__ float sbuf[8];
  long b = blockIdx.x;
  float v = hid[b*DD + threadIdx.x] * w2[threadIdx.x];   // block 512
  #pragma unroll
  for (int o = 32; o > 0; o >>= 1) v += __shfl_down(v, o, 64);
  if ((threadIdx.x & 63) == 0) sbuf[threadIdx.x>>6] = v;
  __syncthreads();
  if (threadIdx.x == 0){
    float s = 0.0f;
    #pragma unroll
    for (int i = 0; i < 8; i++) s += sbuf[i];
    out[b] = 1.0f/(1.0f + expf(-(s + b2[0])));
  }
}

static size_t ws_needed(int Bc){
  auto al = [](size_t b){ return ((b + 255)/256)*256; };
  size_t BNc = (size_t)Bc*NTOK;
  size_t tot = 0;
  tot += al((12UL*1536 + 36UL*512 + 512UL)*512*2 + 512UL*1024*2); // bf16 weights (+o1)
  tot += al(12UL*1536*4) + al(12UL*512*4);    // qkv bias, f1 bias
  tot += al(BNc*64);                          // stats float2[BNc][8]
  tot += al(BNc*DD*4);                        // h fp32
  tot += al(BNc*DD*2);                        // obuf bf16 (attn out)
  tot += al(BNc*1536*2);                      // qkv bf16
  tot += al((size_t)Bc*NHEAD*HD*256*2);       // vt
  tot += al(128UL*1536*2) + al(128UL*512*4);  // cat bf16, hid fp32
  tot += 4096;
  return tot;
}

extern "C" void kernel_launch(void* const* d_in, const int* in_sizes, int n_in,
                              void* d_out, int out_size, void* d_ws, size_t ws_size,
                              hipStream_t stream){
  (void)in_sizes; (void)n_in; (void)out_size;
  const float* x      = (const float*)d_in[0];
  const float* w_left = (const float*)d_in[1];
  const float* b_left = (const float*)d_in[2];
  const float* w_right= (const float*)d_in[3];
  const float* b_right= (const float*)d_in[4];
  const float* w_mid  = (const float*)d_in[5];
  const float* b_mid  = (const float*)d_in[6];
  const float* pos    = (const float*)d_in[7];
  const float* cls    = (const float*)d_in[8];
  const float* ln1_g  = (const float*)d_in[9];
  const float* ln1_b  = (const float*)d_in[10];
  const float* ln2_g  = (const float*)d_in[11];
  const float* ln2_b  = (const float*)d_in[12];
  const float* wq     = (const float*)d_in[13];
  const float* wk     = (const float*)d_in[14];
  const float* wv     = (const float*)d_in[15];
  const float* wo     = (const float*)d_in[16];
  const float* fc1w   = (const float*)d_in[17];
  const float* fc1b   = (const float*)d_in[18];
  const float* fc2w   = (const float*)d_in[19];
  const float* fc2b   = (const float*)d_in[20];
  const float* o1w    = (const float*)d_in[21];
  const float* o1b    = (const float*)d_in[22];
  const float* o2w    = (const float*)d_in[23];
  const float* o2b    = (const float*)d_in[24];
  float* out = (float*)d_out;

  int Bc = 128;
  while (Bc > 1 && ws_needed(Bc) > ws_size) Bc >>= 1;
  const int nchunk = BATCH / Bc;
  const long BNc  = (long)Bc*NTOK;

  char* wsp = (char*)d_ws;
  auto carveb = [&](size_t bytes)->void*{
    void* p = (void*)wsp;
    wsp += ((bytes + 255)/256)*256;
    return p;
  };
  ushort_t* wt    = (ushort_t*)carveb((12UL*1536 + 36UL*512 + 512UL)*512*2 + 512UL*1024*2);
  float*    qkvb  = (float*)   carveb(12UL*1536*4);
  float*    f1b2  = (float*)   carveb(12UL*512*4);
  float2*   stats = (float2*)  carveb(BNc*64);
  float*    h     = (float*)   carveb(BNc*DD*4);
  ushort_t* obuf  = (ushort_t*)carveb(BNc*DD*2);
  ushort_t* qkv   = (ushort_t*)carveb(BNc*1536*2);
  ushort_t* vt    = (ushort_t*)carveb((size_t)Bc*NHEAD*HD*256*2);
  ushort_t* cat   = (ushort_t*)carveb(128UL*1536*2);
  float*    hid   = (float*)   carveb(128UL*512*4);

  ushort_t* wtqkv = wt;
  ushort_t* wto   = wt + 12UL*1536*512;
  ushort_t* wt1   = wto + 12UL*512*512;
  ushort_t* wt2   = wt1 + 12UL*512*512;
  ushort_t* wth   = wt2 + 12UL*512*512;     // o1w^T: [512][1536]

  {
    dim3 g(16,16,12), b(32,8);
    long dpq = 1536L*512, dps = 512L*512;
    wtrans_kernel<<<g,b,0,stream>>>(wtqkv,             wq,   ln1_g, 512, dpq, dps, 512);
    wtrans_kernel<<<g,b,0,stream>>>(wtqkv + 512L*512,  wk,   ln1_g, 512, dpq, dps, 512);
    wtrans_kernel<<<g,b,0,stream>>>(wtqkv + 1024L*512, wv,   ln1_g, 512, dpq, dps, 512);
    wtrans_kernel<<<g,b,0,stream>>>(wto,               wo,   nullptr, 512, dps, dps, 0);
    wtrans_kernel<<<g,b,0,stream>>>(wt1,               fc1w, ln2_g, 512, dps, dps, 512);
    wtrans_kernel<<<g,b,0,stream>>>(wt2,               fc2w, nullptr, 512, dps, dps, 0);
    wtrans_kernel<<<dim3(16,48,1),b,0,stream>>>(wth,   o1w,  nullptr, 1536, 0, 0, 0);
    dim3 gp(2,12);
    bias_prep<<<gp,256,0,stream>>>(qkvb,        nullptr, ln1_b, wq,   1536, 512);
    bias_prep<<<gp,256,0,stream>>>(qkvb + 512,  nullptr, ln1_b, wk,   1536, 512);
    bias_prep<<<gp,256,0,stream>>>(qkvb + 1024, nullptr, ln1_b, wv,   1536, 512);
    bias_prep<<<gp,256,0,stream>>>(f1b2,        fc1b,    ln2_b, fc1w, 512,  512);
  }

  const float* wsel[3] = {w_left, w_right, w_mid};
  const float* bsel[3] = {b_left, b_right, b_mid};

  dim3 blk(256);
  const float alpha = 0.08838834764831845f;  // 1/sqrt(128)
  int mt = (int)((BNc + 127)/128);
  dim3 gqkv(mt, 12, 1);
  dim3 gdd(mt, 4, 1);
  dim3 gfl(4, 1, Bc*NHEAD);
  dim3 gvt(4, 8, Bc*NHEAD);

  for (int br = 0; br < 3; br++){
    for (int c = 0; c < nchunk; c++){
      int b0 = c*Bc;
      embed_kernel<<<(int)BNc, 128, 0, stream>>>(h, stats, x, wsel[br], bsel[br], pos, cls, br, b0);
      for (int l = 0; l < 4; l++){
        long wi = (long)br*4 + l;
        const ushort_t* Wqkv = wtqkv + wi*1536*512;
        const ushort_t* Wo   = wto + wi*DD*DD;
        const ushort_t* F1   = wt1 + wi*DD*DD;
        const ushort_t* F2   = wt2 + wi*DD*DD;
        const float* QB  = qkvb + wi*1536;
        const float* F1b = f1b2 + wi*DD;
        const float* F2b = fc2b + wi*DD;

        // QKV = LN1(h) @ Wqkv' + beta@Wqkv (LN fused into A-staging)
        gemm_bt_mfma<<<gqkv, blk, 0, stream>>>(nullptr, h, stats, nullptr, DD,
                                               Wqkv, DD, qkv, 1536, QB,
                                               (int)BNc, 1536, DD, GF_LNA|GF_BIAS|GF_OBF16, 1.0f);
        vtrans_kernel<<<gvt, dim3(32,8), 0, stream>>>(vt, qkv + 1024);
        flash_kernel<<<gfl, blk, 0, stream>>>(obuf, qkv, vt, alpha);
        // h += o @ Wo; emits LN2 stats
        gemm_bt_mfma<<<gdd, blk, 0, stream>>>(obuf, nullptr, nullptr, stats, DD,
                                              Wo, DD, h, DD, nullptr,
                                              (int)BNc, DD, DD, GF_ADDC|GF_STATS, 1.0f);
        // m = gelu(LN2(h) @ F1' + b1')
        gemm_bt_mfma<<<gdd, blk, 0, stream>>>(nullptr, h, stats, nullptr, DD,
                                              F1, DD, qkv, DD, F1b,
                                              (int)BNc, DD, DD, GF_LNA|GF_BIAS|GF_GELU|GF_OBF16, 1.0f);
        // h += m @ F2 + b2; emits next LN1 stats
        gemm_bt_mfma<<<gdd, blk, 0, stream>>>(qkv, nullptr, nullptr, stats, DD,
                                              F2, DD, h, DD, F2b,
                                              (int)BNc, DD, DD, GF_BIAS|GF_ADDC|GF_STATS, 1.0f);
      }
      copy_cls<<<Bc, 512, 0, stream>>>(cat, h, br, b0);
    }
  }
  dim3 ghd(1, 4, 1);
  gemm_bt_mfma<<<ghd, blk, 0, stream>>>(cat, nullptr, nullptr, nullptr, 1536,
                                        wth, 1536, hid, DD, o1b,
                                        128, DD, 1536, GF_BIAS|GF_GELU, 1.0f);
  head2_kernel<<<BATCH, 512, 0, stream>>>(out, hid, o2w, o2b);
}

// Round 10
// 7021.582 us; speedup vs baseline: 1.3321x; 1.3321x over previous
//
#include <hip/hip_runtime.h>
#include <math.h>

#define DD   512
#define BATCH 128
#define NTOK 251
#define NHEAD 4
#define HD   128

#define GF_ADDC   1
#define GF_BIAS   2
#define GF_GELU   4
#define GF_OBF16  8

typedef unsigned short ushort_t;
typedef __attribute__((ext_vector_type(8))) short bf16x8;
typedef __attribute__((ext_vector_type(4))) float f32x4;

__constant__ int c_cols[3][12] = {
  {8,10,12,22,24,26, 9,11,13,23,25,27},
  {2, 4, 6,28,30,32, 3, 5, 7,29,31,33},
  {0,14,16,18,20, 1,15,17,19,21, 0, 0}
};
__constant__ int c_ncols[3] = {12,12,10};

__device__ __forceinline__ float gelu_f(float v){
  return 0.5f*v*(1.0f + erff(v*0.70710678118654752440f));
}
__device__ __forceinline__ ushort_t f2b(float v){   // RNE float->bf16
  union { float f; unsigned u; } x; x.f = v;
  unsigned r = x.u + 0x7fffu + ((x.u >> 16) & 1u);
  return (ushort_t)(r >> 16);
}
__device__ __forceinline__ float b2f(ushort_t u){
  union { unsigned u; float f; } x; x.u = ((unsigned)u) << 16; return x.f;
}
__device__ __forceinline__ void async_copy16(const void* g, void* l){
  __builtin_amdgcn_global_load_lds(
      (const __attribute__((address_space(1))) unsigned*)g,
      (__attribute__((address_space(3))) unsigned*)l, 16, 0, 0);
}

// ---- weight convert+transpose: D[n*ldD+k] = bf16(S[k*512+n]) per plane ----
__global__ __launch_bounds__(256) void wtrans_kernel(ushort_t* __restrict__ dst,
                                                     const float* __restrict__ src,
                                                     long ldD, long dstPlane, long srcPlane){
  __shared__ float tile[32][33];
  long mat = blockIdx.z;
  const float* S = src + mat*srcPlane;
  ushort_t* D = dst + mat*dstPlane;
  int n0 = blockIdx.x*32, k0 = blockIdx.y*32;
  for (int r = threadIdx.y; r < 32; r += 8)
    tile[r][threadIdx.x] = S[(long)(k0+r)*DD + n0 + threadIdx.x];
  __syncthreads();
  for (int r = threadIdx.y; r < 32; r += 8)
    D[(long)(n0+r)*ldD + k0 + threadIdx.x] = f2b(tile[threadIdx.x][r]);
}

// ---- embed -> bf16 h ----
__global__ void embed_kernel(ushort_t* __restrict__ h, const float* __restrict__ x,
                             const float* __restrict__ w, const float* __restrict__ bias,
                             const float* __restrict__ pos, const float* __restrict__ cls,
                             int br, int b0){
  long bt = blockIdx.x;
  int  t  = (int)(bt % NTOK);
  long b  = b0 + bt / NTOK;
  ushort_t* outr = h + bt*DD;
  if (t == 0){
    for (int d = threadIdx.x; d < DD; d += 128) outr[d] = f2b(cls[d] + pos[d]);
    return;
  }
  const float* xr = x + (b*(NTOK-1) + (t-1))*34;
  int nc = c_ncols[br];
  float xs[12];
  for (int j = 0; j < 12; j++) xs[j] = (j < nc) ? xr[c_cols[br][j]] : 0.0f;
  const float* posr = pos + (long)t*DD;
  for (int d = threadIdx.x; d < DD; d += 128){
    float acc = bias[d] + posr[d];
    for (int j = 0; j < nc; j++) acc = fmaf(xs[j], w[j*DD + d], acc);
    outr[d] = f2b(acc);
  }
}

// ---- layernorm bf16 -> bf16: one wave per row, shfl-only, no LDS ----
__global__ __launch_bounds__(256) void ln_kernel(ushort_t* __restrict__ out,
                                                 const ushort_t* __restrict__ in,
                                                 const float* __restrict__ g,
                                                 const float* __restrict__ beta){
  long row = (long)blockIdx.x*4 + (threadIdx.x>>6);
  int lane = threadIdx.x & 63;
  union { uint4 v; ushort_t s[8]; } raw;
  raw.v = *(const uint4*)(in + row*DD + lane*8);
  float d[8];
  #pragma unroll
  for (int e = 0; e < 8; e++) d[e] = b2f(raw.s[e]);
  float s = 0.0f;
  #pragma unroll
  for (int e = 0; e < 8; e++) s += d[e];
  #pragma unroll
  for (int o = 32; o > 0; o >>= 1) s += __shfl_xor(s, o, 64);
  float mu = s * (1.0f/512.0f);
  float q = 0.0f;
  #pragma unroll
  for (int e = 0; e < 8; e++){ d[e] -= mu; q += d[e]*d[e]; }
  #pragma unroll
  for (int o = 32; o > 0; o >>= 1) q += __shfl_xor(q, o, 64);
  float r = rsqrtf(q*(1.0f/512.0f) + 1e-5f);
  const float* gp = g + lane*8;
  const float* bp = beta + lane*8;
  float4 g0 = *(const float4*)gp, g1 = *(const float4*)(gp+4);
  float4 e0 = *(const float4*)bp, e1 = *(const float4*)(bp+4);
  float gg[8] = {g0.x,g0.y,g0.z,g0.w,g1.x,g1.y,g1.z,g1.w};
  float bb[8] = {e0.x,e0.y,e0.z,e0.w,e1.x,e1.y,e1.z,e1.w};
  ushort_t o8[8];
  #pragma unroll
  for (int e = 0; e < 8; e++) o8[e] = f2b(d[e]*r*gg[e] + bb[e]);
  *(uint4*)(out + row*DD + lane*8) = *(const uint4*)o8;
}

// ---- V^T per (b,h): vt[plane][d][t] (ld 256, t-pad zeroed) ----
__global__ __launch_bounds__(256) void vtrans_kernel(ushort_t* __restrict__ vt,
                                                     const ushort_t* __restrict__ v){
  __shared__ ushort_t tile[32][33];
  int b = blockIdx.z >> 2, hh = blockIdx.z & 3;
  const ushort_t* src = v + (long)b*NTOK*1536 + hh*HD;
  ushort_t* dst = vt + (long)blockIdx.z*HD*256;
  int t0 = blockIdx.y*32, d0 = blockIdx.x*32;
  int tx = threadIdx.x, ty = threadIdx.y;
  for (int r = ty; r < 32; r += 8){
    int t = t0 + r;
    tile[r][tx] = (t < NTOK) ? src[(long)t*1536 + d0 + tx] : (ushort_t)0;
  }
  __syncthreads();
  for (int r = ty; r < 32; r += 8)
    dst[(long)(d0 + r)*256 + t0 + tx] = tile[tx][r];
}

// ---- fused flash attention (Q hoisted to regs) ----
__global__ __launch_bounds__(256) void flash_kernel(
    ushort_t* __restrict__ o, const ushort_t* __restrict__ qkv,
    const ushort_t* __restrict__ vt, float alpha){
  __shared__ __align__(16) ushort_t Ps[64*136];
  int bh = blockIdx.z, b = bh>>2, hh = bh&3;
  int q0 = blockIdx.x*64;
  const ushort_t* Qg = qkv + (long)b*NTOK*1536 + hh*HD;
  const ushort_t* Kg = Qg + 512;
  const ushort_t* Vg = vt + (long)bh*HD*256;
  int tid = threadIdx.x, w = tid>>6, lane = tid&63;
  int quad = lane>>4, l15 = lane&15;
  int qrow = q0 + w*16 + l15;
  const ushort_t* qptr = Qg + (long)qrow*1536;
  bool qvalid = qrow < NTOK;

  bf16x8 qf[4];
  #pragma unroll
  for (int kc = 0; kc < 4; kc++){
    if (qvalid) qf[kc] = *(const bf16x8*)(qptr + kc*32 + quad*8);
    else        qf[kc] = (bf16x8){0,0,0,0,0,0,0,0};
  }

  f32x4 oacc[8] = {};
  float mrow[4], lrow[4];
  #pragma unroll
  for (int r = 0; r < 4; r++){ mrow[r] = -1e30f; lrow[r] = 0.0f; }

  #pragma unroll
  for (int nt = 0; nt < 2; nt++){
    f32x4 s[8] = {};
    #pragma unroll
    for (int kc = 0; kc < 4; kc++){
      #pragma unroll
      for (int j = 0; j < 8; j++){
        long t = nt*128 + j*16 + l15;
        bf16x8 bf = *(const bf16x8*)(Kg + t*1536 + kc*32 + quad*8);
        s[j] = __builtin_amdgcn_mfma_f32_16x16x32_bf16(qf[kc], bf, s[j], 0, 0, 0);
      }
    }
    #pragma unroll
    for (int r = 0; r < 4; r++){
      float mx = -1e30f;
      #pragma unroll
      for (int j = 0; j < 8; j++){
        int t = nt*128 + j*16 + l15;
        float v = (t < NTOK) ? s[j][r]*alpha : -1e30f;
        s[j][r] = v; mx = fmaxf(mx, v);
      }
      mx = fmaxf(mx, __shfl_xor(mx,1)); mx = fmaxf(mx, __shfl_xor(mx,2));
      mx = fmaxf(mx, __shfl_xor(mx,4)); mx = fmaxf(mx, __shfl_xor(mx,8));
      float Mn  = fmaxf(mrow[r], mx);
      float fac = __expf(mrow[r] - Mn);
      mrow[r] = Mn;
      float sum = 0.0f;
      #pragma unroll
      for (int j = 0; j < 8; j++){
        float e = __expf(s[j][r] - Mn);
        s[j][r] = e; sum += e;
      }
      sum += __shfl_xor(sum,1); sum += __shfl_xor(sum,2);
      sum += __shfl_xor(sum,4); sum += __shfl_xor(sum,8);
      lrow[r] = lrow[r]*fac + sum;
      #pragma unroll
      for (int j = 0; j < 8; j++) oacc[j][r] *= fac;
      #pragma unroll
      for (int j = 0; j < 8; j++)
        Ps[(w*16 + quad*4 + r)*136 + j*16 + l15] = f2b(s[j][r]);
    }
    #pragma unroll
    for (int tc = 0; tc < 4; tc++){
      bf16x8 af = *(const bf16x8*)&Ps[(w*16 + l15)*136 + tc*32 + quad*8];
      #pragma unroll
      for (int j = 0; j < 8; j++){
        bf16x8 bf = *(const bf16x8*)(Vg + (long)(j*16 + l15)*256 + nt*128 + tc*32 + quad*8);
        oacc[j] = __builtin_amdgcn_mfma_f32_16x16x32_bf16(af, bf, oacc[j], 0, 0, 0);
      }
    }
  }
  #pragma unroll
  for (int r = 0; r < 4; r++){
    int q = q0 + w*16 + quad*4 + r;
    if (q >= NTOK) continue;
    float invl = 1.0f / lrow[r];
    ushort_t* orow = o + ((long)b*NTOK + q)*512 + hh*128;
    #pragma unroll
    for (int j = 0; j < 8; j++)
      orow[j*16 + l15] = f2b(oacc[j][r]*invl);
  }
}

// ---- MFMA GEMM: C = alpha*A[M,K] @ Bt[N,K]^T; block 128x128, wave 64x64 ----
// GF_ADDC+GF_OBF16: C is bf16 (residual stream). GF_ADDC alone: C fp32.
__global__ __launch_bounds__(256) void gemm_bt_mfma(
    const ushort_t* __restrict__ A, long lda, long sA1, long sA2,
    const ushort_t* __restrict__ Bt, long ldb, long sB1, long sB2,
    void* __restrict__ Cp, long ldc, long sC1, long sC2,
    const float* __restrict__ bias, int M, int N, int K,
    int zdiv, int flags, float alpha){
  int bz = blockIdx.z;
  A  += (long)(bz/zdiv)*sA1 + (long)(bz%zdiv)*sA2;
  Bt += (long)(bz/zdiv)*sB1 + (long)(bz%zdiv)*sB2;
  long coff = (long)(bz/zdiv)*sC1 + (long)(bz%zdiv)*sC2;

  __shared__ __align__(16) ushort_t As[128*32];
  __shared__ __align__(16) ushort_t Bs[128*32];

  int tid = threadIdx.x;
  int wave = tid >> 6, lane = tid & 63;
  int quad = lane >> 4, l15 = lane & 15;
  int wm = (wave >> 1) * 64, wn = (wave & 1) * 64;
  int m0 = blockIdx.x * 128, n0 = blockIdx.y * 128;

  f32x4 acc[4][4] = {};
  bool fast = (m0 + 128 <= M) && (n0 + 128 <= N) && ((K & 31) == 0);

  if (fast){
    int rloc = wave*16 + (lane >> 2);
    int pos  = lane & 3;
    const ushort_t* A0 = A + (long)m0*lda;
    const ushort_t* B0 = Bt + (long)n0*ldb;
    for (int k0 = 0; k0 < K; k0 += 32){
      #pragma unroll
      for (int c = 0; c < 2; c++){
        int r  = c*64 + rloc;
        int cg = pos ^ ((r >> 1) & 3);
        long koff = k0 + cg*8;
        async_copy16(A0 + (long)r*lda + koff, (void*)&As[(c*256 + wave*64)*8]);
        async_copy16(B0 + (long)r*ldb + koff, (void*)&Bs[(c*256 + wave*64)*8]);
      }
      __syncthreads();
      bf16x8 af[4], bfv[4];
      #pragma unroll
      for (int i = 0; i < 4; i++){
        int row = wm + i*16 + l15;
        af[i] = *(const bf16x8*)&As[row*32 + ((quad ^ ((row>>1)&3)) << 3)];
      }
      #pragma unroll
      for (int j = 0; j < 4; j++){
        int row = wn + j*16 + l15;
        bfv[j] = *(const bf16x8*)&Bs[row*32 + ((quad ^ ((row>>1)&3)) << 3)];
      }
      #pragma unroll
      for (int i = 0; i < 4; i++)
        #pragma unroll
        for (int j = 0; j < 4; j++)
          acc[i][j] = __builtin_amdgcn_mfma_f32_16x16x32_bf16(af[i], bfv[j], acc[i][j], 0, 0, 0);
      __syncthreads();
    }
  } else {
    int nk = (K + 31) >> 5;
    for (int kt = 0; kt < nk; kt++){
      int k0 = kt << 5;
      #pragma unroll
      for (int c = 0; c < 2; c++){
        int q = c*256 + tid;
        int r = q >> 2;
        int gk = k0 + (((q & 3) ^ ((r >> 1) & 3)) << 3);
        {
          int gm = m0 + r;
          uint4 va;
          if (gm < M && gk + 8 <= K){
            va = *(const uint4*)(A + (long)gm*lda + gk);
          } else {
            ushort_t t[8];
            #pragma unroll
            for (int e = 0; e < 8; e++){
              int kk = gk + e;
              t[e] = (gm < M && kk < K) ? A[(long)gm*lda + kk] : (ushort_t)0;
            }
            va = *(const uint4*)t;
          }
          *(uint4*)&As[r*32 + (q & 3)*8] = va;
        }
        {
          int gn = n0 + r;
          uint4 vb;
          if (gn < N && gk + 8 <= K){
            vb = *(const uint4*)(Bt + (long)gn*ldb + gk);
          } else {
            ushort_t t[8];
            #pragma unroll
            for (int e = 0; e < 8; e++){
              int kk = gk + e;
              t[e] = (gn < N && kk < K) ? Bt[(long)gn*ldb + kk] : (ushort_t)0;
            }
            vb = *(const uint4*)t;
          }
          *(uint4*)&Bs[r*32 + (q & 3)*8] = vb;
        }
      }
      __syncthreads();
      bf16x8 af[4], bfv[4];
      #pragma unroll
      for (int i = 0; i < 4; i++){
        int row = wm + i*16 + l15;
        af[i] = *(const bf16x8*)&As[row*32 + ((quad ^ ((row>>1)&3)) << 3)];
      }
      #pragma unroll
      for (int j = 0; j < 4; j++){
        int row = wn + j*16 + l15;
        bfv[j] = *(const bf16x8*)&Bs[row*32 + ((quad ^ ((row>>1)&3)) << 3)];
      }
      #pragma unroll
      for (int i = 0; i < 4; i++)
        #pragma unroll
        for (int j = 0; j < 4; j++)
          acc[i][j] = __builtin_amdgcn_mfma_f32_16x16x32_bf16(af[i], bfv[j], acc[i][j], 0, 0, 0);
      __syncthreads();
    }
  }

  // epilogue: C/D layout col=lane&15, row=quad*4+reg
  #pragma unroll
  for (int i = 0; i < 4; i++){
    int rbase = m0 + wm + i*16 + quad*4;
    #pragma unroll
    for (int j = 0; j < 4; j++){
      int gn = n0 + wn + j*16 + l15;
      if (gn >= N) continue;
      #pragma unroll
      for (int r = 0; r < 4; r++){
        int gm = rbase + r;
        if (gm >= M) continue;
        float v = acc[i][j][r] * alpha;
        if (flags & GF_BIAS) v += bias[gn];
        if (flags & GF_ADDC){
          if (flags & GF_OBF16) v += b2f(((const ushort_t*)Cp)[coff + (long)gm*ldc + gn]);
          else                  v += ((const float*)Cp)[coff + (long)gm*ldc + gn];
        }
        if (flags & GF_GELU) v = gelu_f(v);
        if (flags & GF_OBF16){
          ((ushort_t*)Cp)[coff + (long)gm*ldc + gn] = f2b(v);
        } else {
          ((float*)Cp)[coff + (long)gm*ldc + gn] = v;
        }
      }
    }
  }
}

__global__ void copy_cls(ushort_t* __restrict__ cat, const ushort_t* __restrict__ h,
                         int br, int b0){
  long b = blockIdx.x;
  int d = threadIdx.x;            // block 512
  cat[(b0+b)*1536 + (long)br*512 + d] = h[b*(long)NTOK*DD + d];
}

__global__ void head2_kernel(float* __restrict__ out, const float* __restrict__ hid,
                             const float* __restrict__ w2, const float* __restrict__ b2){
  __shared__ float sbuf[8];
  long b = blockIdx.x;
  float v = hid[b*DD + threadIdx.x] * w2[threadIdx.x];   // block 512
  #pragma unroll
  for (int o = 32; o > 0; o >>= 1) v += __shfl_down(v, o, 64);
  if ((threadIdx.x & 63) == 0) sbuf[threadIdx.x>>6] = v;
  __syncthreads();
  if (threadIdx.x == 0){
    float s = 0.0f;
    #pragma unroll
    for (int i = 0; i < 8; i++) s += sbuf[i];
    out[b] = 1.0f/(1.0f + expf(-(s + b2[0])));
  }
}

static size_t ws_needed(int Bc){
  auto al = [](size_t b){ return ((b + 255)/256)*256; };
  size_t BNc = (size_t)Bc*NTOK;
  size_t tot = 0;
  tot += al((12UL*1536 + 36UL*512 + 512UL)*512*2 + 512UL*1024*2); // bf16 weights (+o1)
  tot += al(BNc*DD*2);                        // h bf16 (residual)
  tot += al(BNc*DD*2);                        // z bf16
  tot += al(BNc*1536*2);                      // qkv bf16
  tot += al((size_t)Bc*NHEAD*HD*256*2);       // vt
  tot += al(128UL*1536*2) + al(128UL*512*4);  // cat bf16, hid fp32
  tot += 4096;
  return tot;
}

extern "C" void kernel_launch(void* const* d_in, const int* in_sizes, int n_in,
                              void* d_out, int out_size, void* d_ws, size_t ws_size,
                              hipStream_t stream){
  (void)in_sizes; (void)n_in; (void)out_size;
  const float* x      = (const float*)d_in[0];
  const float* w_left = (const float*)d_in[1];
  const float* b_left = (const float*)d_in[2];
  const float* w_right= (const float*)d_in[3];
  const float* b_right= (const float*)d_in[4];
  const float* w_mid  = (const float*)d_in[5];
  const float* b_mid  = (const float*)d_in[6];
  const float* pos    = (const float*)d_in[7];
  const float* cls    = (const float*)d_in[8];
  const float* ln1_g  = (const float*)d_in[9];
  const float* ln1_b  = (const float*)d_in[10];
  const float* ln2_g  = (const float*)d_in[11];
  const float* ln2_b  = (const float*)d_in[12];
  const float* wq     = (const float*)d_in[13];
  const float* wk     = (const float*)d_in[14];
  const float* wv     = (const float*)d_in[15];
  const float* wo     = (const float*)d_in[16];
  const float* fc1w   = (const float*)d_in[17];
  const float* fc1b   = (const float*)d_in[18];
  const float* fc2w   = (const float*)d_in[19];
  const float* fc2b   = (const float*)d_in[20];
  const float* o1w    = (const float*)d_in[21];
  const float* o1b    = (const float*)d_in[22];
  const float* o2w    = (const float*)d_in[23];
  const float* o2b    = (const float*)d_in[24];
  float* out = (float*)d_out;

  int Bc = 128;
  while (Bc > 1 && ws_needed(Bc) > ws_size) Bc >>= 1;
  const int nchunk = BATCH / Bc;
  const long BNc  = (long)Bc*NTOK;

  char* wsp = (char*)d_ws;
  auto carveb = [&](size_t bytes)->void*{
    void* p = (void*)wsp;
    wsp += ((bytes + 255)/256)*256;
    return p;
  };
  ushort_t* wt   = (ushort_t*)carveb((12UL*1536 + 36UL*512 + 512UL)*512*2 + 512UL*1024*2);
  ushort_t* h    = (ushort_t*)carveb(BNc*DD*2);
  ushort_t* z    = (ushort_t*)carveb(BNc*DD*2);
  ushort_t* qkv  = (ushort_t*)carveb(BNc*1536*2);
  ushort_t* vt   = (ushort_t*)carveb((size_t)Bc*NHEAD*HD*256*2);
  ushort_t* cat  = (ushort_t*)carveb(128UL*1536*2);
  float*    hid  = (float*)   carveb(128UL*512*4);

  ushort_t* wtqkv = wt;
  ushort_t* wto   = wt + 12UL*1536*512;
  ushort_t* wt1   = wto + 12UL*512*512;
  ushort_t* wt2   = wt1 + 12UL*512*512;
  ushort_t* wth   = wt2 + 12UL*512*512;     // o1w^T: [512][1536]

  {
    dim3 g(16,16,12), b(32,8);
    long dpq = 1536L*512, dps = 512L*512;
    wtrans_kernel<<<g,b,0,stream>>>(wtqkv,             wq,   512, dpq, dps);
    wtrans_kernel<<<g,b,0,stream>>>(wtqkv + 512L*512,  wk,   512, dpq, dps);
    wtrans_kernel<<<g,b,0,stream>>>(wtqkv + 1024L*512, wv,   512, dpq, dps);
    wtrans_kernel<<<g,b,0,stream>>>(wto,               wo,   512, dps, dps);
    wtrans_kernel<<<g,b,0,stream>>>(wt1,               fc1w, 512, dps, dps);
    wtrans_kernel<<<g,b,0,stream>>>(wt2,               fc2w, 512, dps, dps);
    wtrans_kernel<<<dim3(16,48,1),b,0,stream>>>(wth,   o1w, 1536, 0, 0);
  }

  const float* wsel[3] = {w_left, w_right, w_mid};
  const float* bsel[3] = {b_left, b_right, b_mid};

  dim3 blk(256);
  const float alpha = 0.08838834764831845f;  // 1/sqrt(128)
  int mt = (int)((BNc + 127)/128);
  dim3 gqkv(mt, 12, 1);
  dim3 gdd(mt, 4, 1);
  dim3 gfl(4, 1, Bc*NHEAD);
  dim3 gvt(4, 8, Bc*NHEAD);

  for (int br = 0; br < 3; br++){
    for (int c = 0; c < nchunk; c++){
      int b0 = c*Bc;
      embed_kernel<<<(int)BNc, 128, 0, stream>>>(h, x, wsel[br], bsel[br], pos, cls, br, b0);
      for (int l = 0; l < 4; l++){
        long wi = (long)br*4 + l;
        const float* g1 = ln1_g + wi*DD; const float* be1 = ln1_b + wi*DD;
        const float* g2 = ln2_g + wi*DD; const float* be2 = ln2_b + wi*DD;
        const ushort_t* Wqkv = wtqkv + wi*1536*512;
        const ushort_t* Wo   = wto + wi*DD*DD;
        const ushort_t* F1   = wt1 + wi*DD*DD;
        const ushort_t* F2   = wt2 + wi*DD*DD;
        const float* F1b = fc1b + wi*DD;  const float* F2b = fc2b + wi*DD;

        ln_kernel<<<(int)(BNc/4), 256, 0, stream>>>(z, h, g1, be1);
        gemm_bt_mfma<<<gqkv, blk, 0, stream>>>(z,DD,0,0, Wqkv,DD,0,0, qkv,1536,0,0, nullptr,
                                               (int)BNc,1536,DD, 1, GF_OBF16, 1.0f);
        vtrans_kernel<<<gvt, dim3(32,8), 0, stream>>>(vt, qkv + 1024);
        flash_kernel<<<gfl, blk, 0, stream>>>(z, qkv, vt, alpha);
        // h += o @ Wo  (bf16 residual read+write)
        gemm_bt_mfma<<<gdd, blk, 0, stream>>>(z,DD,0,0, Wo,DD,0,0, h,DD,0,0, nullptr,
                                              (int)BNc,DD,DD, 1, GF_ADDC|GF_OBF16, 1.0f);
        ln_kernel<<<(int)(BNc/4), 256, 0, stream>>>(z, h, g2, be2);
        gemm_bt_mfma<<<gdd, blk, 0, stream>>>(z,DD,0,0, F1,DD,0,0, qkv,DD,0,0, F1b,
                                              (int)BNc,DD,DD, 1, GF_BIAS|GF_GELU|GF_OBF16, 1.0f);
        gemm_bt_mfma<<<gdd, blk, 0, stream>>>(qkv,DD,0,0, F2,DD,0,0, h,DD,0,0, F2b,
                                              (int)BNc,DD,DD, 1, GF_BIAS|GF_ADDC|GF_OBF16, 1.0f);
      }
      copy_cls<<<Bc, 512, 0, stream>>>(cat, h, br, b0);
    }
  }
  // head: hid = gelu(cat @ o1w + o1b) via MFMA (M=128,N=512,K=1536), then head2
  dim3 ghd(1, 4, 1);
  gemm_bt_mfma<<<ghd, blk, 0, stream>>>(cat,1536,0,0, wth,1536,0,0, hid,DD,0,0, o1b,
                                        128,DD,1536, 1, GF_BIAS|GF_GELU, 1.0f);
  head2_kernel<<<BATCH, 512, 0, stream>>>(out, hid, o2w, o2b);
}